// Round 4
// baseline (116.367 us; speedup 1.0000x reference)
//
#include <hip/hip_runtime.h>

// Problem constants (fixed by setup_inputs in the reference)
#define B_  8
#define T_  2048
#define D_  1024
#define H_  8
#define S_  128

// --------------------------------------------------------------------------
// Fully fused: one block per (b,s) span. No logits round-trip through HBM.
//
// Phase A (proven k1 wave body): wave wv computes logits for span rows
//   wv*8 .. wv*8+7. Rows begin..begin+31 are always in-bounds (begin<=2015,
//   begin+31 <= 2046 < T), so no bounds checks; rows >= width get garbage
//   logits that phase B masks to -1e30 (-> weight exactly 0).
//   Per 256-col chunk the wave holds kw fragments for all 8 heads in
//   registers and streams 8 feat rows through them. 63-shuffle compaction
//   leaves lane l with the full dot for (row wv*8 + (l>>3), head l&7);
//   one contiguous 256 B LDS store per wave builds the 32x8 logit slab.
//
// Phase B (proven k2 register softmax): after one barrier, every wave
//   redundantly loads the whole slab (float4 per lane: t = 4l..4l+3,
//   t = i*8+h), masks t >= width*8, and reduces per-head with
//   parity-preserving shfl_xor over offsets {2,4,8,16,32}.
//
// Phase C (proven k2 pooling): thread covers cols [wv*256+lane*4, +4);
//   weights broadcast with 2 shuffles per span row; feat rows re-read from
//   L1/L2 (just fetched in phase A). Fixed 8-row unrolled chunks; rows
//   beyond width carry weight 0.
// --------------------------------------------------------------------------
__global__ __launch_bounds__(256) void pooler_fused(
    const float* __restrict__ feat,    // [B*T, D]
    const int* __restrict__ begins,    // [B*S]
    const int* __restrict__ ends,      // [B*S]
    const float* __restrict__ kw,      // [H, D]
    const float* __restrict__ kb,      // [H]
    float* __restrict__ out)           // [B*S, D]
{
    const int bs   = blockIdx.x;            // 0 .. B_*S_-1
    const int wv   = threadIdx.x >> 6;
    const int lane = threadIdx.x & 63;
    const int b    = bs >> 7;               // / S_

    const int begin = begins[bs];
    const int width = ends[bs] - begin;     // 1..32
    const size_t row0 = (size_t)b * T_ + begin;

    __shared__ __align__(16) float lg[32 * H_];   // 1 KB logit slab

    // ---------------- Phase A: span logits ----------------
    float acc[64];
#pragma unroll
    for (int j = 0; j < 64; ++j) acc[j] = 0.f;

    const int r0 = wv * 8;
#pragma unroll
    for (int c = 0; c < 4; ++c) {
        float4 kf[H_];
#pragma unroll
        for (int h = 0; h < H_; ++h)
            kf[h] = *(const float4*)(kw + h * D_ + c * 256 + lane * 4);
#pragma unroll
        for (int r = 0; r < 8; ++r) {
            float4 fv = *(const float4*)(feat + (row0 + r0 + r) * D_ + c * 256 + lane * 4);
#pragma unroll
            for (int h = 0; h < H_; ++h)
                acc[r * 8 + h] += fv.x * kf[h].x + fv.y * kf[h].y
                                + fv.z * kf[h].z + fv.w * kf[h].w;
        }
    }

    // Value-compacting cross-lane reduce: after 6 steps acc[0] on lane l is
    // the 64-lane sum for original value index l (row r0+(l>>3), head l&7).
#pragma unroll
    for (int s = 0; s < 6; ++s) {
        const int m = 1 << s;
        const bool hi = (lane >> s) & 1;
#pragma unroll
        for (int j = 0; j < (32 >> s); ++j) {
            float mine  = hi ? acc[2 * j + 1] : acc[2 * j];
            float other = hi ? acc[2 * j]     : acc[2 * j + 1];
            acc[j] = mine + __shfl_xor(other, m, 64);
        }
    }

    lg[wv * 64 + lane] = acc[0] + kb[lane & 7];
    __syncthreads();

    // ---------------- Phase B: register softmax (all waves redundant) ------
    float4 lv = *(const float4*)&lg[lane * 4];   // t = 4l..4l+3
    const int w8 = width * H_;
    float v0 = (4 * lane + 0 < w8) ? lv.x : -1e30f;
    float v1 = (4 * lane + 1 < w8) ? lv.y : -1e30f;
    float v2 = (4 * lane + 2 < w8) ? lv.z : -1e30f;
    float v3 = (4 * lane + 3 < w8) ? lv.w : -1e30f;

    float m0 = v0, m1 = v1, m2 = v2, m3 = v3;
#pragma unroll
    for (int off = 2; off <= 32; off <<= 1) {
        m0 = fmaxf(m0, __shfl_xor(m0, off, 64));
        m1 = fmaxf(m1, __shfl_xor(m1, off, 64));
        m2 = fmaxf(m2, __shfl_xor(m2, off, 64));
        m3 = fmaxf(m3, __shfl_xor(m3, off, 64));
    }

    float e0 = __expf(v0 - m0);                  // masked -> exactly 0
    float e1 = __expf(v1 - m1);
    float e2 = __expf(v2 - m2);
    float e3 = __expf(v3 - m3);
    float s0 = e0, s1 = e1, s2 = e2, s3 = e3;
#pragma unroll
    for (int off = 2; off <= 32; off <<= 1) {
        s0 += __shfl_xor(s0, off, 64);
        s1 += __shfl_xor(s1, off, 64);
        s2 += __shfl_xor(s2, off, 64);
        s3 += __shfl_xor(s3, off, 64);
    }
    const float w0 = e0 / s0, w1 = e1 / s1, w2 = e2 / s2, w3 = e3 / s3;

    // ---------------- Phase C: weighted pooling ----------------
    // weight w[i][hh] lives on lane 2i+p, element (wv&1)*2 + (lane>=32),
    // with p = wv>>1 (wave-uniform).
    const int p = wv >> 1;
    const float wlo = (wv & 1) ? w2 : w0;
    const float whi = (wv & 1) ? w3 : w1;
    const bool hiHalf = (lane >= 32);

    const int colbase = wv * 256 + lane * 4;
    const float* fbase = feat + row0 * D_ + colbase;

    float4 oacc = make_float4(0.f, 0.f, 0.f, 0.f);
    const int nch = (width + 7) >> 3;            // 1..4 chunks of 8 rows
    for (int ch = 0; ch < nch; ++ch) {
#pragma unroll
        for (int k = 0; k < 8; ++k) {
            const int i = ch * 8 + k;
            const float t0 = __shfl(wlo, 2 * i + p, 64);
            const float t1 = __shfl(whi, 2 * i + p, 64);
            const float wt = hiHalf ? t1 : t0;
            const float4 fv = *(const float4*)(fbase + (size_t)i * D_);
            oacc.x += wt * fv.x;
            oacc.y += wt * fv.y;
            oacc.z += wt * fv.z;
            oacc.w += wt * fv.w;
        }
    }

    *(float4*)(out + (size_t)bs * D_ + colbase) = oacc;
}

extern "C" void kernel_launch(void* const* d_in, const int* in_sizes, int n_in,
                              void* d_out, int out_size, void* d_ws, size_t ws_size,
                              hipStream_t stream) {
    const float* feat   = (const float*)d_in[0];   // features f32 [B,T,D]
    const int*   begins = (const int*)d_in[1];     // int32 [B,S]
    const int*   ends   = (const int*)d_in[2];     // int32 [B,S]
    const float* kw     = (const float*)d_in[3];   // key_w f32 [H,D]
    const float* kb     = (const float*)d_in[4];   // key_b f32 [H]
    float*       out    = (float*)d_out;           // f32 [B*S, D]
    (void)d_ws; (void)ws_size;

    pooler_fused<<<B_ * S_, 256, 0, stream>>>(feat, begins, ends, kw, kb, out);
}

// Round 5
// 111.704 us; speedup vs baseline: 1.0417x; 1.0417x over previous
//
#include <hip/hip_runtime.h>

// Problem constants (fixed by setup_inputs in the reference)
#define B_  8
#define T_  2048
#define D_  1024
#define H_  8
#define S_  128

// --------------------------------------------------------------------------
// Fully fused: one block per (b,s) span.
//
// Stage 0: cooperatively stage kw (32 KB) into LDS (one L2 read per block
//   instead of one per wave).
// Phase A: wave wv computes logits for span rows wv*8..wv*8+7, but ONLY if
//   r0 < width (wave-uniform gate; avg width 16.6 -> ~37% of phase-A work
//   skipped). Rows begin..begin+31 are always in-bounds (begin <= 2015).
//   Per 256-col chunk the wave reads kw fragments for all 8 heads from LDS
//   (contiguous ds_read_b128 -> conflict-free) and streams 8 feat rows
//   through them. 63-shuffle compaction leaves lane l with the dot for
//   (row wv*8 + (l>>3), head l&7); one 256 B LDS store per wave.
// Phase B: every wave redundantly loads the 32x8 logit slab (float4/lane,
//   t = 4l..4l+3, t = i*8+h), masks t >= width*8 BEFORE any arithmetic
//   (garbage rows from gated waves are never touched), reduces per-head
//   with parity-preserving shfl_xor over offsets {2,4,8,16,32}.
// Phase C: thread covers cols [wv*256+lane*4, +4); weights broadcast with
//   2 shuffles per span row; feat re-read from L1/L2 (fetched in phase A).
//   Fixed 8-row unrolled chunks, ceil(width/8) of them; rows beyond width
//   carry weight exactly 0.
// --------------------------------------------------------------------------
__global__ __launch_bounds__(256) void pooler_fused(
    const float* __restrict__ feat,    // [B*T, D]
    const int* __restrict__ begins,    // [B*S]
    const int* __restrict__ ends,      // [B*S]
    const float* __restrict__ kw,      // [H, D]
    const float* __restrict__ kb,      // [H]
    float* __restrict__ out)           // [B*S, D]
{
    const int bs   = blockIdx.x;            // 0 .. B_*S_-1
    const int wv   = threadIdx.x >> 6;
    const int lane = threadIdx.x & 63;
    const int b    = bs >> 7;               // / S_

    const int begin = begins[bs];
    const int width = ends[bs] - begin;     // 1..32
    const size_t row0 = (size_t)b * T_ + begin;

    __shared__ __align__(16) float kwl[H_ * D_];  // 32 KB staged key_w
    __shared__ __align__(16) float lg[32 * H_];   // 1 KB logit slab

    // ---------------- Stage 0: kw -> LDS (coalesced float4 copy) ----------
    {
        const float4* src = (const float4*)kw;
        float4*       dst = (float4*)kwl;
        const int tid = threadIdx.x;
#pragma unroll
        for (int j = 0; j < 8; ++j)
            dst[tid + 256 * j] = src[tid + 256 * j];
    }
    __syncthreads();

    // ---------------- Phase A: span logits (gated per wave) ----------------
    const int r0 = wv * 8;
    if (r0 < width) {
        float acc[64];
#pragma unroll
        for (int j = 0; j < 64; ++j) acc[j] = 0.f;

#pragma unroll
        for (int c = 0; c < 4; ++c) {
            float4 kf[H_];
#pragma unroll
            for (int h = 0; h < H_; ++h)
                kf[h] = *(const float4*)&kwl[h * D_ + c * 256 + lane * 4];
#pragma unroll
            for (int r = 0; r < 8; ++r) {
                float4 fv = *(const float4*)(feat + (row0 + r0 + r) * D_ + c * 256 + lane * 4);
#pragma unroll
                for (int h = 0; h < H_; ++h)
                    acc[r * 8 + h] += fv.x * kf[h].x + fv.y * kf[h].y
                                    + fv.z * kf[h].z + fv.w * kf[h].w;
            }
        }

        // Value-compacting cross-lane reduce: after 6 steps acc[0] on lane l
        // is the 64-lane sum for original value index l (row r0+(l>>3), head l&7).
#pragma unroll
        for (int s = 0; s < 6; ++s) {
            const int m = 1 << s;
            const bool hi = (lane >> s) & 1;
#pragma unroll
            for (int j = 0; j < (32 >> s); ++j) {
                float mine  = hi ? acc[2 * j + 1] : acc[2 * j];
                float other = hi ? acc[2 * j]     : acc[2 * j + 1];
                acc[j] = mine + __shfl_xor(other, m, 64);
            }
        }

        lg[wv * 64 + lane] = acc[0] + kb[lane & 7];
    }
    __syncthreads();

    // ---------------- Phase B: register softmax (all waves redundant) ------
    float4 lv = *(const float4*)&lg[lane * 4];   // t = 4l..4l+3
    const int w8 = width * H_;
    float v0 = (4 * lane + 0 < w8) ? lv.x : -1e30f;
    float v1 = (4 * lane + 1 < w8) ? lv.y : -1e30f;
    float v2 = (4 * lane + 2 < w8) ? lv.z : -1e30f;
    float v3 = (4 * lane + 3 < w8) ? lv.w : -1e30f;

    float m0 = v0, m1 = v1, m2 = v2, m3 = v3;
#pragma unroll
    for (int off = 2; off <= 32; off <<= 1) {
        m0 = fmaxf(m0, __shfl_xor(m0, off, 64));
        m1 = fmaxf(m1, __shfl_xor(m1, off, 64));
        m2 = fmaxf(m2, __shfl_xor(m2, off, 64));
        m3 = fmaxf(m3, __shfl_xor(m3, off, 64));
    }

    float e0 = __expf(v0 - m0);                  // masked -> exactly 0
    float e1 = __expf(v1 - m1);
    float e2 = __expf(v2 - m2);
    float e3 = __expf(v3 - m3);
    float s0 = e0, s1 = e1, s2 = e2, s3 = e3;
#pragma unroll
    for (int off = 2; off <= 32; off <<= 1) {
        s0 += __shfl_xor(s0, off, 64);
        s1 += __shfl_xor(s1, off, 64);
        s2 += __shfl_xor(s2, off, 64);
        s3 += __shfl_xor(s3, off, 64);
    }
    const float w0 = e0 / s0, w1 = e1 / s1, w2 = e2 / s2, w3 = e3 / s3;

    // ---------------- Phase C: weighted pooling ----------------
    // weight w[i][hh] lives on lane 2i+p, element (wv&1)*2 + (lane>=32),
    // with p = wv>>1 (wave-uniform).
    const int p = wv >> 1;
    const float wlo = (wv & 1) ? w2 : w0;
    const float whi = (wv & 1) ? w3 : w1;
    const bool hiHalf = (lane >= 32);

    const int colbase = wv * 256 + lane * 4;
    const float* fbase = feat + row0 * D_ + colbase;

    float4 oacc = make_float4(0.f, 0.f, 0.f, 0.f);
    const int nch = (width + 7) >> 3;            // 1..4 chunks of 8 rows
    for (int ch = 0; ch < nch; ++ch) {
#pragma unroll
        for (int k = 0; k < 8; ++k) {
            const int i = ch * 8 + k;
            const float t0 = __shfl(wlo, 2 * i + p, 64);
            const float t1 = __shfl(whi, 2 * i + p, 64);
            const float wt = hiHalf ? t1 : t0;
            const float4 fv = *(const float4*)(fbase + (size_t)i * D_);
            oacc.x += wt * fv.x;
            oacc.y += wt * fv.y;
            oacc.z += wt * fv.z;
            oacc.w += wt * fv.w;
        }
    }

    *(float4*)(out + (size_t)bs * D_ + colbase) = oacc;
}

extern "C" void kernel_launch(void* const* d_in, const int* in_sizes, int n_in,
                              void* d_out, int out_size, void* d_ws, size_t ws_size,
                              hipStream_t stream) {
    const float* feat   = (const float*)d_in[0];   // features f32 [B,T,D]
    const int*   begins = (const int*)d_in[1];     // int32 [B,S]
    const int*   ends   = (const int*)d_in[2];     // int32 [B,S]
    const float* kw     = (const float*)d_in[3];   // key_w f32 [H,D]
    const float* kb     = (const float*)d_in[4];   // key_b f32 [H]
    float*       out    = (float*)d_out;           // f32 [B*S, D]
    (void)d_ws; (void)ws_size;

    pooler_fused<<<B_ * S_, 256, 0, stream>>>(feat, begins, ends, kw, kb, out);
}